// Round 1
// baseline (22033.516 us; speedup 1.0000x reference)
//
#include <hip/hip_runtime.h>
#include <stdint.h>

#define HH 256
#define TT 512
#define NBATCH 256
#define K0 768          // prev_out(256) + audio(256) + h1(256)
#define K1 512          // h1n(256) + h2(256)
#define NROWS 1024      // 4*H gate rows
#define NFEAT 128
#define NROWS_TOT (NBATCH*TT)   // 131072

typedef unsigned int u32;
typedef unsigned short u16;

// ---------- ws layout (bytes) ----------
#define OFF_WT0   0                        // 768*1024 bf16 = 1572864
#define OFF_WT1   1572864                  // 512*1024 bf16 = 1048576
#define OFF_W1T   2621440                  // 256*128 bf16  = 65536
#define OFF_BC0   2686976                  // 1024 f32
#define OFF_BC1   2691072                  // 1024 f32
#define OFF_GSUM  2695168                  // 128 f32
#define OFF_GSQ   (2695168 + 512)          // 128 f32
#define OFF_Y     2696192                  // 131072*128 f32 = 67108864

__device__ __forceinline__ float sigf(float x) { return 1.0f / (1.0f + __expf(-x)); }
__device__ __forceinline__ float tanh_fast(float x) { return 1.0f - 2.0f / (__expf(2.0f * x) + 1.0f); }

__device__ __forceinline__ u16 f2bf(float f) {
    u32 u = __float_as_uint(f);
    u32 r = (u + 0x7fffu + ((u >> 16) & 1u)) >> 16;   // RNE; weights are finite
    return (u16)r;
}

// ---------------- kernel 1: weight transpose/convert + bias combine + zero stats -----
__global__ void prep_kernel(const float* __restrict__ Wih0, const float* __restrict__ Whh0,
                            const float* __restrict__ bih0, const float* __restrict__ bhh0,
                            const float* __restrict__ Wih1, const float* __restrict__ Whh1,
                            const float* __restrict__ bih1, const float* __restrict__ bhh1,
                            const float* __restrict__ W1,
                            u16* __restrict__ WT0, u16* __restrict__ WT1, u16* __restrict__ W1T,
                            float* __restrict__ bc0, float* __restrict__ bc1,
                            float* __restrict__ gsum, float* __restrict__ gsq) {
    int idx = blockIdx.x * 256 + threadIdx.x;
    const int n0 = K0 * NROWS;         // 786432
    const int n1 = K1 * NROWS;         // 524288
    const int n2 = 256 * NFEAT;        // 32768
    if (idx < n0) {
        int k = idx >> 10, r = idx & 1023;
        float v = (k < 512) ? Wih0[r * 512 + k] : Whh0[r * 256 + (k - 512)];
        WT0[idx] = f2bf(v);
    } else if (idx < n0 + n1) {
        int j = idx - n0;
        int k = j >> 10, r = j & 1023;
        float v = (k < 256) ? Wih1[r * 256 + k] : Whh1[r * 256 + (k - 256)];
        WT1[j] = f2bf(v);
    } else if (idx < n0 + n1 + n2) {
        int j = idx - n0 - n1;
        int k = j >> 7, f = j & 127;
        W1T[j] = f2bf(W1[f * 256 + k]);
    } else if (idx < n0 + n1 + n2 + 1024) {
        int j = idx - n0 - n1 - n2;
        bc0[j] = bih0[j] + bhh0[j];
    } else if (idx < n0 + n1 + n2 + 2048) {
        int j = idx - n0 - n1 - n2 - 1024;
        bc1[j] = bih1[j] + bhh1[j];
    } else if (idx < n0 + n1 + n2 + 2048 + 256) {
        int j = idx - n0 - n1 - n2 - 2048;
        if (j < 128) gsum[j] = 0.0f; else gsq[j - 128] = 0.0f;
    }
}

// ---------------- kernel 2: persistent per-batch recurrent LSTM + fused head GEMV ----
__global__ __launch_bounds__(512) void lstm_seq_kernel(
    const float* __restrict__ audio, const float* __restrict__ s_rt,
    const u32* __restrict__ W0u,     // WT0 as uint pairs: [k][512] pairs (rows 2t,2t+1)
    const u32* __restrict__ W1u,     // WT1 same
    const u32* __restrict__ W1Tu,    // W1T as uint pairs (copied to LDS)
    const float* __restrict__ bc0, const float* __restrict__ bc1,
    const float* __restrict__ b1,
    float* __restrict__ ybuf, float* __restrict__ gsum, float* __restrict__ gsq) {
    __shared__ float x0[K0];          // [prev_out | a_t | h1]
    __shared__ float x1[K1];          // [h1n | h2]
    __shared__ float zz[NROWS];
    __shared__ float c1s[HH], c2s[HH];
    __shared__ float bc0s[NROWS], bc1s[NROWS], b1s[NFEAT];
    __shared__ u16 W1s[256 * NFEAT]; // [k][f] bf16, 64KB

    const int tid = threadIdx.x;
    const int b = blockIdx.x;

    // stage constants
    for (int i = tid; i < NROWS; i += 512) { bc0s[i] = bc0[i]; bc1s[i] = bc1[i]; }
    if (tid < NFEAT) b1s[tid] = b1[tid];
    {
        u32* W1s32 = (u32*)W1s;
        for (int i = tid; i < 256 * NFEAT / 2; i += 512) W1s32[i] = W1Tu[i];
    }
    const float* aud_b = audio + (size_t)b * TT * HH;
    // init state
    if (tid < HH) {
        float s = 0.0f;
        const float* sp = s_rt + ((size_t)b * 16) * HH + tid;
        #pragma unroll
        for (int l = 0; l < 16; ++l) s += sp[l * HH];
        x0[tid] = s * (1.0f / 16.0f);       // prev_out
        x0[512 + tid] = 0.0f;               // h1
        x1[tid] = 0.0f;                     // h1n slot
        x1[256 + tid] = 0.0f;               // h2
        c1s[tid] = 0.0f;
        c2s[tid] = 0.0f;
        x0[256 + tid] = aud_b[tid];         // a_0
    }
    __syncthreads();

    float ysum = 0.0f, ysq = 0.0f;

    for (int t = 0; t < TT; ++t) {
        // prefetch a_{t+1} (threads 256..511)
        float a_next = 0.0f;
        if (tid >= 256 && t + 1 < TT) a_next = aud_b[(size_t)(t + 1) * HH + (tid - 256)];

        // ---- phase A: layer0 gates, rows 2tid, 2tid+1, K=768 ----
        {
            float acc0 = bc0s[2 * tid], acc1 = bc0s[2 * tid + 1];
            const u32* Wp = W0u + tid;
            #pragma unroll 8
            for (int k = 0; k < K0; ++k) {
                u32 w = Wp[k * 512];
                float xk = x0[k];
                acc0 = fmaf(xk, __uint_as_float(w << 16), acc0);
                acc1 = fmaf(xk, __uint_as_float(w & 0xffff0000u), acc1);
            }
            zz[2 * tid] = acc0; zz[2 * tid + 1] = acc1;
        }
        __syncthreads();
        // ---- phase B: layer0 cell update ----
        if (tid < HH) {
            float zi = zz[tid], zf = zz[256 + tid], zg = zz[512 + tid], zo = zz[768 + tid];
            float c = sigf(zf) * c1s[tid] + sigf(zi) * tanh_fast(zg);
            c1s[tid] = c;
            float h = sigf(zo) * tanh_fast(c);
            x0[512 + tid] = h;   // h1 for next step's layer0
            x1[tid] = h;         // layer1 input
        }
        __syncthreads();
        // ---- phase C: layer1 gates, K=512 ----
        {
            float acc0 = bc1s[2 * tid], acc1 = bc1s[2 * tid + 1];
            const u32* Wp = W1u + tid;
            #pragma unroll 8
            for (int k = 0; k < K1; ++k) {
                u32 w = Wp[k * 512];
                float xk = x1[k];
                acc0 = fmaf(xk, __uint_as_float(w << 16), acc0);
                acc1 = fmaf(xk, __uint_as_float(w & 0xffff0000u), acc1);
            }
            zz[2 * tid] = acc0; zz[2 * tid + 1] = acc1;
        }
        __syncthreads();
        // ---- phase D1: layer1 cell update ----
        if (tid < HH) {
            float zi = zz[tid], zf = zz[256 + tid], zg = zz[512 + tid], zo = zz[768 + tid];
            float c = sigf(zf) * c2s[tid] + sigf(zi) * tanh_fast(zg);
            c2s[tid] = c;
            float h = sigf(zo) * tanh_fast(c);
            x0[tid] = h;         // prev_out for next step
            x1[256 + tid] = h;   // h2 for next step's layer1
        }
        __syncthreads();
        // ---- phase D2: head y = h2 @ W1.T + b1 (threads<128); a_{t+1} -> LDS (threads>=256)
        if (tid < NFEAT) {
            float acc = b1s[tid];
            #pragma unroll 8
            for (int k = 0; k < 256; ++k) {
                float w = __uint_as_float(((u32)W1s[k * NFEAT + tid]) << 16);
                acc = fmaf(x0[k], w, acc);
            }
            ybuf[((size_t)b * TT + t) * NFEAT + tid] = acc;
            ysum += acc; ysq += acc * acc;
        } else if (tid >= 256) {
            if (t + 1 < TT) x0[256 + (tid - 256)] = a_next;
        }
        __syncthreads();
    }
    if (tid < NFEAT) {
        atomicAdd(&gsum[tid], ysum);
        atomicAdd(&gsq[tid], ysq);
    }
}

// ---------------- kernel 3: BN(train) + ReLU + Linear(128->6) ----------------------
__global__ __launch_bounds__(256) void head_kernel(
    const float* __restrict__ ybuf, const float* __restrict__ gsum, const float* __restrict__ gsq,
    const float* __restrict__ gamma, const float* __restrict__ beta,
    const float* __restrict__ W2, const float* __restrict__ b2,
    float* __restrict__ out) {
    __shared__ float tile[256][129];
    __shared__ float scale[NFEAT], shift[NFEAT];
    __shared__ float W2s[6 * NFEAT];
    __shared__ float b2s[6];
    const int tid = threadIdx.x;
    const size_t row0 = (size_t)blockIdx.x * 256;

    if (tid < NFEAT) {
        const float invN = 1.0f / (float)NROWS_TOT;
        float mu = gsum[tid] * invN;
        float var = gsq[tid] * invN - mu * mu;
        float inv = rsqrtf(var + 1e-5f);
        float sc = gamma[tid] * inv;
        scale[tid] = sc;
        shift[tid] = beta[tid] - mu * sc;
    }
    for (int i = tid; i < 6 * NFEAT; i += 256) W2s[i] = W2[i];
    if (tid < 6) b2s[tid] = b2[tid];

    const float* ysrc = ybuf + row0 * NFEAT;
    #pragma unroll 4
    for (int i = 0; i < 128; ++i) {
        int idx = i * 256 + tid;
        tile[idx >> 7][idx & 127] = ysrc[idx];
    }
    __syncthreads();

    float a0 = b2s[0], a1 = b2s[1], a2 = b2s[2], a3 = b2s[3], a4 = b2s[4], a5 = b2s[5];
    #pragma unroll 4
    for (int f = 0; f < NFEAT; ++f) {
        float v = fmaxf(fmaf(tile[tid][f], scale[f], shift[f]), 0.0f);
        a0 = fmaf(v, W2s[0 * NFEAT + f], a0);
        a1 = fmaf(v, W2s[1 * NFEAT + f], a1);
        a2 = fmaf(v, W2s[2 * NFEAT + f], a2);
        a3 = fmaf(v, W2s[3 * NFEAT + f], a3);
        a4 = fmaf(v, W2s[4 * NFEAT + f], a4);
        a5 = fmaf(v, W2s[5 * NFEAT + f], a5);
    }
    float* op = out + (row0 + tid) * 6;
    op[0] = a0; op[1] = a1; op[2] = a2; op[3] = a3; op[4] = a4; op[5] = a5;
}

extern "C" void kernel_launch(void* const* d_in, const int* in_sizes, int n_in,
                              void* d_out, int out_size, void* d_ws, size_t ws_size,
                              hipStream_t stream) {
    // inputs (setup_inputs order): 0 rt(unused), 1 audio, 2 s_rt, 3..6 l0 w/b, 7..10 l1 w/b,
    // 11 W1, 12 b1, 13 gamma, 14 beta, 15 W2, 16 b2, 17 max_len(unused)
    const float* audio = (const float*)d_in[1];
    const float* s_rt  = (const float*)d_in[2];
    const float* Wih0  = (const float*)d_in[3];
    const float* Whh0  = (const float*)d_in[4];
    const float* bih0  = (const float*)d_in[5];
    const float* bhh0  = (const float*)d_in[6];
    const float* Wih1  = (const float*)d_in[7];
    const float* Whh1  = (const float*)d_in[8];
    const float* bih1  = (const float*)d_in[9];
    const float* bhh1  = (const float*)d_in[10];
    const float* W1    = (const float*)d_in[11];
    const float* b1    = (const float*)d_in[12];
    const float* gamma = (const float*)d_in[13];
    const float* beta  = (const float*)d_in[14];
    const float* W2    = (const float*)d_in[15];
    const float* b2    = (const float*)d_in[16];

    char* ws = (char*)d_ws;
    u16* WT0   = (u16*)(ws + OFF_WT0);
    u16* WT1   = (u16*)(ws + OFF_WT1);
    u16* W1T   = (u16*)(ws + OFF_W1T);
    float* bc0 = (float*)(ws + OFF_BC0);
    float* bc1 = (float*)(ws + OFF_BC1);
    float* gsum = (float*)(ws + OFF_GSUM);
    float* gsq  = (float*)(ws + OFF_GSQ);
    float* ybuf = (float*)(ws + OFF_Y);
    float* out  = (float*)d_out;

    // prep: 786432+524288+32768+1024+1024+256 = 1345792 elements = 5257 * 256
    prep_kernel<<<5257, 256, 0, stream>>>(Wih0, Whh0, bih0, bhh0, Wih1, Whh1, bih1, bhh1,
                                          W1, WT0, WT1, W1T, bc0, bc1, gsum, gsq);

    lstm_seq_kernel<<<NBATCH, 512, 0, stream>>>(audio, s_rt,
                                                (const u32*)WT0, (const u32*)WT1, (const u32*)W1T,
                                                bc0, bc1, b1, ybuf, gsum, gsq);

    head_kernel<<<NROWS_TOT / 256, 256, 0, stream>>>(ybuf, gsum, gsq, gamma, beta, W2, b2, out);
}

// Round 2
// 18099.565 us; speedup vs baseline: 1.2174x; 1.2174x over previous
//
#include <hip/hip_runtime.h>
#include <stdint.h>

typedef unsigned int u32;
typedef unsigned short u16;
typedef _Float16 f16;
typedef _Float16 h2_t __attribute__((ext_vector_type(2)));

#define HH 256
#define TT 512
#define NB 256
#define NG 8        // batch groups (32 batches each)
#define GW 32       // WGs per group
#define BG 32       // batches per group
#define NF 128
#define NTOT (NB*TT)

#define RL 32            // local gate rows per layer per WG
#define XW 776           // X row length in f16 (768 + 8 pad)
#define XWU 388
#define W0W 776          // layer0 weight row f16 (768 + pad)
#define W0WU 388
#define W1W 520          // layer1 weight row f16 (512 + pad)
#define W1WU 260
#define WHW 264          // head weight row f16 (256 + pad)
#define WHWU 132

// ---- ws layout (bytes) ----
#define OFF_WF0   0u           // 32*32*776*2      = 1,589,248
#define OFF_WF1   1589248u     // 32*32*520*2      = 1,064,960
#define OFF_WH    2654208u     // 32*4*264*2       =    67,584
#define OFF_GSUM  2730496u     // 128 f32
#define OFF_GSQ   2731008u     // 128 f32
#define OFF_CTR   2731520u     // 512 u32 (16 counters, 128B apart)
#define OFF_GH1   2733568u     // 8*32*256 f16 = 131,072
#define OFF_GH2   2864640u     // 131,072
#define OFF_Y     2995712u     // 131072*128 f16 = 33,554,432

__device__ __forceinline__ float sigf(float x) { return 1.0f / (1.0f + __expf(-x)); }
__device__ __forceinline__ float tanh_fast(float x) { return 1.0f - 2.0f / (__expf(2.0f * x) + 1.0f); }

__device__ __forceinline__ float fdot2(u32 a, u32 b, float c) {
    return __builtin_amdgcn_fdot2(__builtin_bit_cast(h2_t, a),
                                  __builtin_bit_cast(h2_t, b), c, false);
}

#define DOT8(A, B, WV, XV) do { \
    A = fdot2((WV).x, (XV).x, A); B = fdot2((WV).y, (XV).y, B); \
    A = fdot2((WV).z, (XV).z, A); B = fdot2((WV).w, (XV).w, B); } while (0)

// monotonic 32-WG group barrier; release/acquire via threadfence
#define GROUP_BARRIER(CTRP, TGT) do { \
    if (tid == 0) { \
        __threadfence(); \
        __hip_atomic_fetch_add((CTRP), 1u, __ATOMIC_RELAXED, __HIP_MEMORY_SCOPE_AGENT); \
        int guard_ = 0; \
        while (__hip_atomic_load((CTRP), __ATOMIC_RELAXED, __HIP_MEMORY_SCOPE_AGENT) < (TGT) \
               && ++guard_ < 200000000) { __builtin_amdgcn_s_sleep(2); } \
        __threadfence(); \
    } \
    __syncthreads(); } while (0)

// ---------------- prep: reformat weights to per-WG f16 layouts, zero stats/ctrs ----
__global__ void prep_kernel(const float* __restrict__ Wih0, const float* __restrict__ Whh0,
                            const float* __restrict__ Wih1, const float* __restrict__ Whh1,
                            const float* __restrict__ W1,
                            f16* __restrict__ WF0, f16* __restrict__ WF1, f16* __restrict__ WHo,
                            float* __restrict__ gz, u32* __restrict__ ctr) {
    int idx = blockIdx.x * 256 + threadIdx.x;
    const int n0 = GW * RL * W0W;     // 794624
    const int n1 = GW * RL * W1W;     // 532480
    const int n2 = GW * 4 * WHW;      // 33792
    if (idx < n0) {
        int w = idx / (RL * W0W);
        int rem = idx - w * (RL * W0W);
        int j = rem / W0W;
        int k = rem - j * W0W;
        int r = ((j >> 3) << 8) + 8 * w + (j & 7);
        float v = 0.f;
        if (k < 512) v = Wih0[r * 512 + k];
        else if (k < 768) v = Whh0[r * 256 + (k - 512)];
        WF0[idx] = (f16)v;
    } else if (idx < n0 + n1) {
        int i2 = idx - n0;
        int w = i2 / (RL * W1W);
        int rem = i2 - w * (RL * W1W);
        int j = rem / W1W;
        int k = rem - j * W1W;
        int r = ((j >> 3) << 8) + 8 * w + (j & 7);
        float v = 0.f;
        if (k < 256) v = Wih1[r * 256 + k];
        else if (k < 512) v = Whh1[r * 256 + (k - 256)];
        WF1[i2] = (f16)v;
    } else if (idx < n0 + n1 + n2) {
        int i2 = idx - n0 - n1;
        int w = i2 / (4 * WHW);
        int rem = i2 - w * (4 * WHW);
        int f = rem / WHW;
        int k = rem - f * WHW;
        float v = (k < 256) ? W1[(4 * w + f) * 256 + k] : 0.f;
        WHo[i2] = (f16)v;
    } else if (idx < n0 + n1 + n2 + 256) {
        gz[idx - n0 - n1 - n2] = 0.f;          // gsum[128] + gsq[128] contiguous
    } else if (idx < n0 + n1 + n2 + 256 + 512) {
        ctr[idx - n0 - n1 - n2 - 256] = 0u;
    }
}

// ---------------- main: 256 WGs = 8 groups x 32 row-slices, weights LDS-resident ----
__global__ __launch_bounds__(512) void lstm_group_kernel(
    const float* __restrict__ audio, const float* __restrict__ s_rt,
    const u32* __restrict__ WF0, const u32* __restrict__ WF1, const u32* __restrict__ WHg,
    const float* __restrict__ bih0, const float* __restrict__ bhh0,
    const float* __restrict__ bih1, const float* __restrict__ bhh1,
    const float* __restrict__ b1,
    f16* __restrict__ gh1, f16* __restrict__ gh2,
    u32* __restrict__ ctr,
    f16* __restrict__ ybuf, float* __restrict__ gsum, float* __restrict__ gsq)
{
    __shared__ f16 WL0[RL][W0W];      // 49664 B
    __shared__ f16 WL1[RL][W1W];      // 33280 B
    __shared__ f16 WHs[4][WHW];       //  2112 B
    __shared__ f16 X[BG][XW];         // 49664 B  [h2/prev_out | a_t | h1]
    __shared__ float zb[RL][33];      //  4224 B
    __shared__ float bc0s[RL], bc1s[RL], b1s[4];

    const int tid = threadIdx.x;
    const int w = blockIdx.x >> 3;    // row-slice 0..31
    const int g = blockIdx.x & 7;     // group 0..7

    // ---- stage weights into LDS ----
    {
        u32* d0 = (u32*)&WL0[0][0];
        const u32* s0 = WF0 + (size_t)w * (RL * W0WU);
        for (int i = tid; i < RL * W0WU; i += 512) d0[i] = s0[i];
        u32* d1 = (u32*)&WL1[0][0];
        const u32* s1 = WF1 + (size_t)w * (RL * W1WU);
        for (int i = tid; i < RL * W1WU; i += 512) d1[i] = s1[i];
        u32* d2 = (u32*)&WHs[0][0];
        const u32* s2 = WHg + (size_t)w * (4 * WHWU);
        for (int i = tid; i < 4 * WHWU; i += 512) d2[i] = s2[i];
    }
    if (tid < RL) {
        int r = ((tid >> 3) << 8) + 8 * w + (tid & 7);
        bc0s[tid] = bih0[r] + bhh0[r];
        bc1s[tid] = bih1[r] + bhh1[r];
    }
    if (tid < 4) b1s[tid] = b1[4 * w + tid];

    // ---- init X: prev_out = mean(s_rt), a_0, h1 = 0 ----
    for (int it = tid; it < BG * 256; it += 512) {
        int b = it >> 8, c = it & 255;
        const float* sp = s_rt + ((size_t)(32 * g + b) * 16) * 256 + c;
        float s = 0.f;
        #pragma unroll
        for (int l = 0; l < 16; ++l) s += sp[l * 256];
        X[b][c] = (f16)(s * 0.0625f);
        X[b][256 + c] = (f16)audio[((size_t)(32 * g + b) * 512) * 256 + c];
    }
    for (int it = tid; it < BG * 128; it += 512) {
        int b = it >> 7, q = it & 127;
        ((u32*)&X[b][512])[q] = 0u;
    }
    float c1 = 0.f, c2 = 0.f;          // cell state for (cb, cj), tid<256
    float ysum = 0.f, ysq = 0.f;       // BN stats for (f, b), tid<128
    __syncthreads();

    u32* ctr1 = ctr + (g * 2 + 0) * 32;
    u32* ctr2 = ctr + (g * 2 + 1) * 32;

    const int rp = tid >> 5;           // 0..15
    const int bb = tid & 31;
    const int r0 = 2 * rp, r1 = 2 * rp + 1;
    const u32* xrow = (const u32*)&X[bb][0];
    const u32* w0r0 = (const u32*)&WL0[r0][0];
    const u32* w0r1 = (const u32*)&WL0[r1][0];
    const u32* w1r0 = (const u32*)&WL1[r0][0];
    const u32* w1r1 = (const u32*)&WL1[r1][0];
    const int cb = tid >> 3, cj = tid & 7;

    for (int t = 0; t < TT; ++t) {
        // ---- A: layer0 gates, K=768, rows r0,r1 x batch bb ----
        {
            float a0 = bc0s[r0], a1 = bc0s[r1], a0b = 0.f, a1b = 0.f;
            #pragma unroll 4
            for (int kk = 0; kk < 384; kk += 8) {
                uint4 xv0 = *(const uint4*)(xrow + kk);
                uint4 xv1 = *(const uint4*)(xrow + kk + 4);
                uint4 wa = *(const uint4*)(w0r0 + kk);
                uint4 wb = *(const uint4*)(w0r0 + kk + 4);
                uint4 wc = *(const uint4*)(w0r1 + kk);
                uint4 wd = *(const uint4*)(w0r1 + kk + 4);
                DOT8(a0, a0b, wa, xv0); DOT8(a0, a0b, wb, xv1);
                DOT8(a1, a1b, wc, xv0); DOT8(a1, a1b, wd, xv1);
            }
            zb[r0][bb] = a0 + a0b;
            zb[r1][bb] = a1 + a1b;
        }
        __syncthreads();
        // ---- B: layer0 cell update (owner h-slice), publish h1n ----
        if (tid < 256) {
            float zi = zb[cj][cb], zf = zb[8 + cj][cb], zg = zb[16 + cj][cb], zo = zb[24 + cj][cb];
            float c = sigf(zf) * c1 + sigf(zi) * tanh_fast(zg);
            c1 = c;
            float h = sigf(zo) * tanh_fast(c);
            gh1[(size_t)(g * 32 + cb) * 256 + 8 * w + cj] = (f16)h;
        }
        __syncthreads();
        GROUP_BARRIER(ctr1, (u32)(32 * (t + 1)));
        // ---- C: gather h1n -> X[.][512..768) ----
        {
            const uint4* src = (const uint4*)gh1;
            for (int it = tid; it < BG * 32; it += 512) {
                int b = it >> 5, q = it & 31;
                uint4 v = src[(g * 32 + b) * 32 + q];
                *(uint4*)&X[b][512 + q * 8] = v;
            }
        }
        __syncthreads();
        // ---- D: layer1 gates, K=512 ([h1n | h2]) ----
        {
            float a0 = bc1s[r0], a1 = bc1s[r1], a0b = 0.f, a1b = 0.f;
            #pragma unroll 4
            for (int kk = 0; kk < 128; kk += 8) {       // h1n part
                uint4 xv0 = *(const uint4*)(xrow + 256 + kk);
                uint4 xv1 = *(const uint4*)(xrow + 260 + kk);
                uint4 wa = *(const uint4*)(w1r0 + kk);
                uint4 wb = *(const uint4*)(w1r0 + kk + 4);
                uint4 wc = *(const uint4*)(w1r1 + kk);
                uint4 wd = *(const uint4*)(w1r1 + kk + 4);
                DOT8(a0, a0b, wa, xv0); DOT8(a0, a0b, wb, xv1);
                DOT8(a1, a1b, wc, xv0); DOT8(a1, a1b, wd, xv1);
            }
            if (t > 0) {                                // h2 part (h2==0 at t=0)
                #pragma unroll 4
                for (int kk = 0; kk < 128; kk += 8) {
                    uint4 xv0 = *(const uint4*)(xrow + kk);
                    uint4 xv1 = *(const uint4*)(xrow + kk + 4);
                    uint4 wa = *(const uint4*)(w1r0 + 128 + kk);
                    uint4 wb = *(const uint4*)(w1r0 + 132 + kk);
                    uint4 wc = *(const uint4*)(w1r1 + 128 + kk);
                    uint4 wd = *(const uint4*)(w1r1 + 132 + kk);
                    DOT8(a0, a0b, wa, xv0); DOT8(a0, a0b, wb, xv1);
                    DOT8(a1, a1b, wc, xv0); DOT8(a1, a1b, wd, xv1);
                }
            }
            zb[r0][bb] = a0 + a0b;
            zb[r1][bb] = a1 + a1b;
        }
        __syncthreads();
        // ---- E: layer1 cell update, publish h2n ----
        if (tid < 256) {
            float zi = zb[cj][cb], zf = zb[8 + cj][cb], zg = zb[16 + cj][cb], zo = zb[24 + cj][cb];
            float c = sigf(zf) * c2 + sigf(zi) * tanh_fast(zg);
            c2 = c;
            float h = sigf(zo) * tanh_fast(c);
            gh2[(size_t)(g * 32 + cb) * 256 + 8 * w + cj] = (f16)h;
        }
        __syncthreads();
        GROUP_BARRIER(ctr2, (u32)(32 * (t + 1)));
        // ---- F: gather h2n -> X[.][0..256); audio t+1 -> X[.][256..512) ----
        {
            const uint4* src = (const uint4*)gh2;
            for (int it = tid; it < BG * 32; it += 512) {
                int b = it >> 5, q = it & 31;
                uint4 v = src[(g * 32 + b) * 32 + q];
                *(uint4*)&X[b][q * 8] = v;
            }
            if (t + 1 < TT) {
                const float4* a4 = (const float4*)audio;
                for (int it = tid; it < BG * 64; it += 512) {
                    int b = it >> 6, q = it & 63;
                    float4 av = a4[((size_t)(32 * g + b) * 512 + (t + 1)) * 64 + q];
                    h2_t p0, p1;
                    p0.x = (f16)av.x; p0.y = (f16)av.y;
                    p1.x = (f16)av.z; p1.y = (f16)av.w;
                    uint2 wv;
                    wv.x = __builtin_bit_cast(u32, p0);
                    wv.y = __builtin_bit_cast(u32, p1);
                    *(uint2*)&X[b][256 + q * 4] = wv;
                }
            }
        }
        __syncthreads();
        // ---- G: head y = W1-slice . h2n + b1 (tid<128); others run ahead into A ----
        if (tid < 128) {
            int f = tid >> 5, b = tid & 31;
            const u32* xh = (const u32*)&X[b][0];
            const u32* wf = (const u32*)&WHs[f][0];
            float a0 = b1s[f], a0b = 0.f;
            #pragma unroll 8
            for (int kk = 0; kk < 128; kk += 4) {
                uint4 wv = *(const uint4*)(wf + kk);
                uint4 xv = *(const uint4*)(xh + kk);
                DOT8(a0, a0b, wv, xv);
            }
            float y = a0 + a0b;
            size_t n = (size_t)(32 * g + b) * 512 + t;
            ybuf[n * 128 + 4 * w + f] = (f16)y;
            ysum += y; ysq += y * y;
        }
        // no sync needed: next A reads X only (F synced), writes zb (G doesn't touch)
    }
    if (tid < 128) {
        for (int m = 16; m >= 1; m >>= 1) {
            ysum += __shfl_xor(ysum, m, 64);
            ysq  += __shfl_xor(ysq, m, 64);
        }
        if ((tid & 31) == 0) {
            int f = tid >> 5;
            atomicAdd(&gsum[4 * w + f], ysum);
            atomicAdd(&gsq[4 * w + f], ysq);
        }
    }
}

// ---------------- final head: BN(train) + ReLU + Linear(128->6) ----------------
__global__ __launch_bounds__(256) void head_kernel(
    const f16* __restrict__ ybuf, const float* __restrict__ gsum, const float* __restrict__ gsq,
    const float* __restrict__ gamma, const float* __restrict__ beta,
    const float* __restrict__ W2, const float* __restrict__ b2,
    float* __restrict__ out)
{
    __shared__ float sc[NF], sh[NF], W2s[6 * NF], b2s[6];
    const int tid = threadIdx.x;
    if (tid < NF) {
        const float invN = 1.f / (float)NTOT;
        float mu = gsum[tid] * invN;
        float var = gsq[tid] * invN - mu * mu;
        float iv = rsqrtf(var + 1e-5f);
        float s = gamma[tid] * iv;
        sc[tid] = s;
        sh[tid] = beta[tid] - mu * s;
    }
    for (int i = tid; i < 6 * NF; i += 256) W2s[i] = W2[i];
    if (tid < 6) b2s[tid] = b2[tid];
    __syncthreads();

    size_t n = (size_t)blockIdx.x * 256 + tid;
    const h2_t* yr = (const h2_t*)(ybuf + n * NF);
    float a0 = b2s[0], a1 = b2s[1], a2 = b2s[2], a3 = b2s[3], a4 = b2s[4], a5 = b2s[5];
    #pragma unroll 8
    for (int p = 0; p < 64; ++p) {
        h2_t v = yr[p];
        int f0 = 2 * p, f1 = 2 * p + 1;
        float v0 = fmaxf(fmaf((float)v.x, sc[f0], sh[f0]), 0.f);
        float v1 = fmaxf(fmaf((float)v.y, sc[f1], sh[f1]), 0.f);
        a0 = fmaf(v0, W2s[0 * NF + f0], a0); a0 = fmaf(v1, W2s[0 * NF + f1], a0);
        a1 = fmaf(v0, W2s[1 * NF + f0], a1); a1 = fmaf(v1, W2s[1 * NF + f1], a1);
        a2 = fmaf(v0, W2s[2 * NF + f0], a2); a2 = fmaf(v1, W2s[2 * NF + f1], a2);
        a3 = fmaf(v0, W2s[3 * NF + f0], a3); a3 = fmaf(v1, W2s[3 * NF + f1], a3);
        a4 = fmaf(v0, W2s[4 * NF + f0], a4); a4 = fmaf(v1, W2s[4 * NF + f1], a4);
        a5 = fmaf(v0, W2s[5 * NF + f0], a5); a5 = fmaf(v1, W2s[5 * NF + f1], a5);
    }
    float* op = out + n * 6;
    op[0] = a0; op[1] = a1; op[2] = a2; op[3] = a3; op[4] = a4; op[5] = a5;
}

extern "C" void kernel_launch(void* const* d_in, const int* in_sizes, int n_in,
                              void* d_out, int out_size, void* d_ws, size_t ws_size,
                              hipStream_t stream) {
    const float* audio = (const float*)d_in[1];
    const float* s_rt  = (const float*)d_in[2];
    const float* Wih0  = (const float*)d_in[3];
    const float* Whh0  = (const float*)d_in[4];
    const float* bih0  = (const float*)d_in[5];
    const float* bhh0  = (const float*)d_in[6];
    const float* Wih1  = (const float*)d_in[7];
    const float* Whh1  = (const float*)d_in[8];
    const float* bih1  = (const float*)d_in[9];
    const float* bhh1  = (const float*)d_in[10];
    const float* W1    = (const float*)d_in[11];
    const float* b1    = (const float*)d_in[12];
    const float* gamma = (const float*)d_in[13];
    const float* beta  = (const float*)d_in[14];
    const float* W2    = (const float*)d_in[15];
    const float* b2    = (const float*)d_in[16];

    char* ws = (char*)d_ws;
    f16* WF0   = (f16*)(ws + OFF_WF0);
    f16* WF1   = (f16*)(ws + OFF_WF1);
    f16* WH    = (f16*)(ws + OFF_WH);
    float* gsum = (float*)(ws + OFF_GSUM);
    float* gsq  = (float*)(ws + OFF_GSQ);
    u32* ctrp   = (u32*)(ws + OFF_CTR);
    f16* gh1    = (f16*)(ws + OFF_GH1);
    f16* gh2    = (f16*)(ws + OFF_GH2);
    f16* ybuf   = (f16*)(ws + OFF_Y);
    float* out  = (float*)d_out;

    // prep: 794624 + 532480 + 33792 + 256 + 512 = 1,361,664 = 5319 * 256
    prep_kernel<<<5319, 256, 0, stream>>>(Wih0, Whh0, Wih1, Whh1, W1,
                                          WF0, WF1, WH, gsum, ctrp);

    lstm_group_kernel<<<256, 512, 0, stream>>>(audio, s_rt,
                                               (const u32*)WF0, (const u32*)WF1, (const u32*)WH,
                                               bih0, bhh0, bih1, bhh1, b1,
                                               gh1, gh2, ctrp, ybuf, gsum, gsq);

    head_kernel<<<NTOT / 256, 256, 0, stream>>>(ybuf, gsum, gsq, gamma, beta, W2, b2, out);
}

// Round 3
// 6692.897 us; speedup vs baseline: 3.2921x; 2.7043x over previous
//
#include <hip/hip_runtime.h>
#include <stdint.h>

typedef unsigned int u32;
typedef unsigned short u16;
typedef unsigned long long u64;
typedef _Float16 f16;
typedef _Float16 h2_t __attribute__((ext_vector_type(2)));

#define HH 256
#define TT 512
#define NB 256
#define NG 8        // batch groups (32 batches each)
#define GW 32       // WGs per group
#define BG 32       // batches per group
#define NF 128
#define NTOT (NB*TT)

#define RL 32            // local gate rows per layer per WG
#define XW 776           // X row length in f16 (768 + 8 pad)
#define W0W 776          // layer0 weight row f16 (768 + pad)
#define W0WU 388
#define W1W 520          // layer1 weight row f16 (512 + pad)
#define W1WU 260
#define WHW 264          // head weight row f16 (256 + pad)
#define WHWU 132

// ---- ws layout (bytes) ----
#define OFF_WF0   0u           // 32*32*776*2      = 1,589,248
#define OFF_WF1   1589248u     // 32*32*520*2      = 1,064,960
#define OFF_WH    2654208u     // 32*4*264*2       =    67,584
#define OFF_GSUM  2730496u     // 128 f32
#define OFF_GSQ   2731008u     // 128 f32
#define OFF_CTR   2731520u     // 512 u32 (16 counters, 128B apart)
#define OFF_GH1   2733568u     // 8*32*256 f16 = 131,072
#define OFF_GH2   2864640u     // 131,072
#define OFF_Y     2995712u     // 131072*128 f16 = 33,554,432

__device__ __forceinline__ float sigf(float x) { return 1.0f / (1.0f + __expf(-x)); }
__device__ __forceinline__ float tanh_fast(float x) { return 1.0f - 2.0f / (__expf(2.0f * x) + 1.0f); }

__device__ __forceinline__ float fdot2(u32 a, u32 b, float c) {
    return __builtin_amdgcn_fdot2(__builtin_bit_cast(h2_t, a),
                                  __builtin_bit_cast(h2_t, b), c, false);
}

#define DOT8(A, B, WV, XV) do { \
    A = fdot2((WV).x, (XV).x, A); B = fdot2((WV).y, (XV).y, B); \
    A = fdot2((WV).z, (XV).z, A); B = fdot2((WV).w, (XV).w, B); } while (0)

// ---------------- prep: reformat weights to per-WG f16 layouts, zero stats/ctrs ----
__global__ void prep_kernel(const float* __restrict__ Wih0, const float* __restrict__ Whh0,
                            const float* __restrict__ Wih1, const float* __restrict__ Whh1,
                            const float* __restrict__ W1,
                            f16* __restrict__ WF0, f16* __restrict__ WF1, f16* __restrict__ WHo,
                            float* __restrict__ gz, u32* __restrict__ ctr) {
    int idx = blockIdx.x * 256 + threadIdx.x;
    const int n0 = GW * RL * W0W;     // 794624
    const int n1 = GW * RL * W1W;     // 532480
    const int n2 = GW * 4 * WHW;      // 33792
    if (idx < n0) {
        int w = idx / (RL * W0W);
        int rem = idx - w * (RL * W0W);
        int j = rem / W0W;
        int k = rem - j * W0W;
        int r = ((j >> 3) << 8) + 8 * w + (j & 7);
        float v = 0.f;
        if (k < 512) v = Wih0[r * 512 + k];
        else if (k < 768) v = Whh0[r * 256 + (k - 512)];
        WF0[idx] = (f16)v;
    } else if (idx < n0 + n1) {
        int i2 = idx - n0;
        int w = i2 / (RL * W1W);
        int rem = i2 - w * (RL * W1W);
        int j = rem / W1W;
        int k = rem - j * W1W;
        int r = ((j >> 3) << 8) + 8 * w + (j & 7);
        float v = 0.f;
        if (k < 256) v = Wih1[r * 256 + k];
        else if (k < 512) v = Whh1[r * 256 + (k - 256)];
        WF1[i2] = (f16)v;
    } else if (idx < n0 + n1 + n2) {
        int i2 = idx - n0 - n1;
        int w = i2 / (4 * WHW);
        int rem = i2 - w * (4 * WHW);
        int f = rem / WHW;
        int k = rem - f * WHW;
        float v = (k < 256) ? W1[(4 * w + f) * 256 + k] : 0.f;
        WHo[i2] = (f16)v;
    } else if (idx < n0 + n1 + n2 + 256) {
        gz[idx - n0 - n1 - n2] = 0.f;          // gsum[128] + gsq[128] contiguous
    } else if (idx < n0 + n1 + n2 + 256 + 512) {
        ctr[idx - n0 - n1 - n2 - 256] = 0u;
    }
}

// ---------------- main: 256 WGs = 8 groups x 32 row-slices, weights LDS-resident ----
__global__ __launch_bounds__(512) void lstm_group_kernel(
    const float* __restrict__ audio, const float* __restrict__ s_rt,
    const u32* __restrict__ WF0, const u32* __restrict__ WF1, const u32* __restrict__ WHg,
    const float* __restrict__ bih0, const float* __restrict__ bhh0,
    const float* __restrict__ bih1, const float* __restrict__ bhh1,
    const float* __restrict__ b1,
    f16* __restrict__ gh1, f16* __restrict__ gh2,
    u32* __restrict__ ctr,
    f16* __restrict__ ybuf, float* __restrict__ gsum, float* __restrict__ gsq)
{
    __shared__ f16 WL0[RL][W0W];      // 49664 B
    __shared__ f16 WL1[RL][W1W];      // 33280 B
    __shared__ f16 WHs[4][WHW];       //  2112 B
    __shared__ f16 X[BG][XW];         // 49664 B  [h2/prev_out | a_t | h1]
    __shared__ float zb[RL][33];      //  4224 B
    __shared__ f16 hst[BG][8];        //   512 B  h staging for publish
    __shared__ float bc0s[RL], bc1s[RL], b1s[4];

    const int tid = threadIdx.x;
    const int w = blockIdx.x >> 3;    // row-slice 0..31
    const int g = blockIdx.x & 7;     // group 0..7

    u64* gh1u = (u64*)gh1;
    u64* gh2u = (u64*)gh2;

    // ---- stage weights into LDS ----
    {
        u32* d0 = (u32*)&WL0[0][0];
        const u32* s0 = WF0 + (size_t)w * (RL * W0WU);
        for (int i = tid; i < RL * W0WU; i += 512) d0[i] = s0[i];
        u32* d1 = (u32*)&WL1[0][0];
        const u32* s1 = WF1 + (size_t)w * (RL * W1WU);
        for (int i = tid; i < RL * W1WU; i += 512) d1[i] = s1[i];
        u32* d2 = (u32*)&WHs[0][0];
        const u32* s2 = WHg + (size_t)w * (4 * WHWU);
        for (int i = tid; i < 4 * WHWU; i += 512) d2[i] = s2[i];
    }
    if (tid < RL) {
        int r = ((tid >> 3) << 8) + 8 * w + (tid & 7);
        bc0s[tid] = bih0[r] + bhh0[r];
        bc1s[tid] = bih1[r] + bhh1[r];
    }
    if (tid < 4) b1s[tid] = b1[4 * w + tid];

    // ---- init X: prev_out = mean(s_rt), a_0, h1 = 0 ----
    for (int it = tid; it < BG * 256; it += 512) {
        int b = it >> 8, c = it & 255;
        const float* sp = s_rt + ((size_t)(32 * g + b) * 16) * 256 + c;
        float s = 0.f;
        #pragma unroll
        for (int l = 0; l < 16; ++l) s += sp[l * 256];
        X[b][c] = (f16)(s * 0.0625f);
        X[b][256 + c] = (f16)audio[((size_t)(32 * g + b) * 512) * 256 + c];
    }
    for (int it = tid; it < BG * 128; it += 512) {
        int b = it >> 7, q = it & 127;
        ((u32*)&X[b][512])[q] = 0u;
    }
    float c1 = 0.f, c2 = 0.f;          // cell state for (cb, cj), tid<256
    float ysum = 0.f, ysq = 0.f;       // BN stats for (f, b), tid<128
    __syncthreads();

    u32* ctr1 = ctr + (g * 2 + 0) * 32;
    u32* ctr2 = ctr + (g * 2 + 1) * 32;

    const int rp = tid >> 5;           // 0..15
    const int bb = tid & 31;
    const int r0 = 2 * rp, r1 = 2 * rp + 1;
    const u32* xrow = (const u32*)&X[bb][0];
    const u32* w0r0 = (const u32*)&WL0[r0][0];
    const u32* w0r1 = (const u32*)&WL0[r1][0];
    const u32* w1r0 = (const u32*)&WL1[r0][0];
    const u32* w1r1 = (const u32*)&WL1[r1][0];
    const int cb = tid >> 3, cj = tid & 7;

    // A-pre for t=0: h1(-1)=0 -> bias only
    float pa0 = bc0s[r0], pa1 = bc0s[r1], pa0b = 0.f, pa1b = 0.f;

    for (int t = 0; t < TT; ++t) {
        // ---- A-post: layer0 gates, cols 0..511 ([h2/prev_out | audio(t)]) ----
        {
            float a0 = pa0, a1 = pa1, a0b = pa0b, a1b = pa1b;
            #pragma unroll 4
            for (int kk = 0; kk < 256; kk += 8) {
                uint4 xv0 = *(const uint4*)(xrow + kk);
                uint4 xv1 = *(const uint4*)(xrow + kk + 4);
                uint4 wa = *(const uint4*)(w0r0 + kk);
                uint4 wb = *(const uint4*)(w0r0 + kk + 4);
                uint4 wc = *(const uint4*)(w0r1 + kk);
                uint4 wd = *(const uint4*)(w0r1 + kk + 4);
                DOT8(a0, a0b, wa, xv0); DOT8(a0, a0b, wb, xv1);
                DOT8(a1, a1b, wc, xv0); DOT8(a1, a1b, wd, xv1);
            }
            zb[r0][bb] = a0 + a0b;
            zb[r1][bb] = a1 + a1b;
        }
        __syncthreads();
        // ---- B: layer0 cell update -> hst ----
        if (tid < 256) {
            float zi = zb[cj][cb], zf = zb[8 + cj][cb], zg = zb[16 + cj][cb], zo = zb[24 + cj][cb];
            float c = sigf(zf) * c1 + sigf(zi) * tanh_fast(zg);
            c1 = c;
            hst[cb][cj] = (f16)(sigf(zo) * tanh_fast(c));
        }
        __syncthreads();
        // ---- barrier1: publish h1 (wave0) overlapped with D-pre (h2 half) ----
        float da0 = bc1s[r0], da1 = bc1s[r1], da0b = 0.f, da1b = 0.f;
        {
            if (tid < 64) {
                u64 v = ((const u64*)hst)[tid];
                __hip_atomic_store(gh1u + (size_t)(g * 32 + (tid >> 1)) * 64 + 2 * w + (tid & 1), v,
                                   __ATOMIC_RELAXED, __HIP_MEMORY_SCOPE_AGENT);
                asm volatile("s_waitcnt vmcnt(0)" ::: "memory");
            }
            if (tid == 0)
                __hip_atomic_fetch_add(ctr1, 1u, __ATOMIC_RELAXED, __HIP_MEMORY_SCOPE_AGENT);
            if (t > 0) {
                #pragma unroll 4
                for (int kk = 0; kk < 128; kk += 8) {   // h2(t-1) = X[0..256)
                    uint4 xv0 = *(const uint4*)(xrow + kk);
                    uint4 xv1 = *(const uint4*)(xrow + kk + 4);
                    uint4 wa = *(const uint4*)(w1r0 + 128 + kk);
                    uint4 wb = *(const uint4*)(w1r0 + 132 + kk);
                    uint4 wc = *(const uint4*)(w1r1 + 128 + kk);
                    uint4 wd = *(const uint4*)(w1r1 + 132 + kk);
                    DOT8(da0, da0b, wa, xv0); DOT8(da0, da0b, wb, xv1);
                    DOT8(da1, da1b, wc, xv0); DOT8(da1, da1b, wd, xv1);
                }
            }
            if (tid == 0) {
                u32 tgt = 32u * (u32)(t + 1);
                int guard_ = 0;
                while (__hip_atomic_load(ctr1, __ATOMIC_RELAXED, __HIP_MEMORY_SCOPE_AGENT) < tgt
                       && ++guard_ < 200000000) { __builtin_amdgcn_s_sleep(2); }
            }
            __syncthreads();
        }
        // ---- C: gather h1(t) -> X[512..768) ----
        for (int it = tid; it < 2048; it += 512) {
            int b = it >> 6, q = it & 63;
            u64 v = __hip_atomic_load(gh1u + (size_t)(g * 32 + b) * 64 + q,
                                      __ATOMIC_RELAXED, __HIP_MEMORY_SCOPE_AGENT);
            *(u64*)&X[b][512 + 4 * q] = v;
        }
        __syncthreads();
        // ---- D-post: layer1 gates, h1n half (cols 0..255) ----
        {
            float a0 = da0, a1 = da1, a0b = da0b, a1b = da1b;
            #pragma unroll 4
            for (int kk = 0; kk < 128; kk += 8) {
                uint4 xv0 = *(const uint4*)(xrow + 256 + kk);
                uint4 xv1 = *(const uint4*)(xrow + 260 + kk);
                uint4 wa = *(const uint4*)(w1r0 + kk);
                uint4 wb = *(const uint4*)(w1r0 + kk + 4);
                uint4 wc = *(const uint4*)(w1r1 + kk);
                uint4 wd = *(const uint4*)(w1r1 + kk + 4);
                DOT8(a0, a0b, wa, xv0); DOT8(a0, a0b, wb, xv1);
                DOT8(a1, a1b, wc, xv0); DOT8(a1, a1b, wd, xv1);
            }
            zb[r0][bb] = a0 + a0b;
            zb[r1][bb] = a1 + a1b;
        }
        __syncthreads();
        // ---- E: layer1 cell update -> hst ----
        if (tid < 256) {
            float zi = zb[cj][cb], zf = zb[8 + cj][cb], zg = zb[16 + cj][cb], zo = zb[24 + cj][cb];
            float c = sigf(zf) * c2 + sigf(zi) * tanh_fast(zg);
            c2 = c;
            hst[cb][cj] = (f16)(sigf(zo) * tanh_fast(c));
        }
        __syncthreads();
        // ---- barrier2: publish h2 (wave0) overlapped with A-next-pre (h1 half) ----
        {
            if (tid < 64) {
                u64 v = ((const u64*)hst)[tid];
                __hip_atomic_store(gh2u + (size_t)(g * 32 + (tid >> 1)) * 64 + 2 * w + (tid & 1), v,
                                   __ATOMIC_RELAXED, __HIP_MEMORY_SCOPE_AGENT);
                asm volatile("s_waitcnt vmcnt(0)" ::: "memory");
            }
            if (tid == 0)
                __hip_atomic_fetch_add(ctr2, 1u, __ATOMIC_RELAXED, __HIP_MEMORY_SCOPE_AGENT);
            pa0 = bc0s[r0]; pa1 = bc0s[r1]; pa0b = 0.f; pa1b = 0.f;
            if (t + 1 < TT) {
                #pragma unroll 4
                for (int kk = 256; kk < 384; kk += 8) {  // h1(t) = X[512..768)
                    uint4 xv0 = *(const uint4*)(xrow + kk);
                    uint4 xv1 = *(const uint4*)(xrow + kk + 4);
                    uint4 wa = *(const uint4*)(w0r0 + kk);
                    uint4 wb = *(const uint4*)(w0r0 + kk + 4);
                    uint4 wc = *(const uint4*)(w0r1 + kk);
                    uint4 wd = *(const uint4*)(w0r1 + kk + 4);
                    DOT8(pa0, pa0b, wa, xv0); DOT8(pa0, pa0b, wb, xv1);
                    DOT8(pa1, pa1b, wc, xv0); DOT8(pa1, pa1b, wd, xv1);
                }
            }
            if (tid == 0) {
                u32 tgt = 32u * (u32)(t + 1);
                int guard_ = 0;
                while (__hip_atomic_load(ctr2, __ATOMIC_RELAXED, __HIP_MEMORY_SCOPE_AGENT) < tgt
                       && ++guard_ < 200000000) { __builtin_amdgcn_s_sleep(2); }
            }
            __syncthreads();
        }
        // ---- F: gather h2(t) -> X[0..256); audio(t+1) -> X[256..512) ----
        {
            for (int it = tid; it < 2048; it += 512) {
                int b = it >> 6, q = it & 63;
                u64 v = __hip_atomic_load(gh2u + (size_t)(g * 32 + b) * 64 + q,
                                          __ATOMIC_RELAXED, __HIP_MEMORY_SCOPE_AGENT);
                *(u64*)&X[b][4 * q] = v;
            }
            if (t + 1 < TT) {
                const float4* a4 = (const float4*)audio;
                for (int it = tid; it < BG * 64; it += 512) {
                    int b = it >> 6, q = it & 63;
                    float4 av = a4[((size_t)(32 * g + b) * 512 + (t + 1)) * 64 + q];
                    h2_t p0, p1;
                    p0.x = (f16)av.x; p0.y = (f16)av.y;
                    p1.x = (f16)av.z; p1.y = (f16)av.w;
                    uint2 wv;
                    wv.x = __builtin_bit_cast(u32, p0);
                    wv.y = __builtin_bit_cast(u32, p1);
                    *(uint2*)&X[b][256 + q * 4] = wv;
                }
            }
        }
        __syncthreads();
        // ---- G: head y = W1-slice . h2(t) + b1 (tid<128); no sync (A-post only reads X) --
        if (tid < 128) {
            int f = tid >> 5, b = tid & 31;
            const u32* xh = (const u32*)&X[b][0];
            const u32* wf = (const u32*)&WHs[f][0];
            float a0 = b1s[f], a0b = 0.f;
            #pragma unroll 8
            for (int kk = 0; kk < 128; kk += 4) {
                uint4 wv = *(const uint4*)(wf + kk);
                uint4 xv = *(const uint4*)(xh + kk);
                DOT8(a0, a0b, wv, xv);
            }
            float y = a0 + a0b;
            size_t n = (size_t)(32 * g + b) * 512 + t;
            ybuf[n * 128 + 4 * w + f] = (f16)y;
            ysum += y; ysq += y * y;
        }
    }
    if (tid < 128) {
        for (int m = 16; m >= 1; m >>= 1) {
            ysum += __shfl_xor(ysum, m, 64);
            ysq  += __shfl_xor(ysq, m, 64);
        }
        if ((tid & 31) == 0) {
            int f = tid >> 5;
            atomicAdd(&gsum[4 * w + f], ysum);
            atomicAdd(&gsq[4 * w + f], ysq);
        }
    }
}

// ---------------- final head: BN(train) + ReLU + Linear(128->6) ----------------
__global__ __launch_bounds__(256) void head_kernel(
    const f16* __restrict__ ybuf, const float* __restrict__ gsum, const float* __restrict__ gsq,
    const float* __restrict__ gamma, const float* __restrict__ beta,
    const float* __restrict__ W2, const float* __restrict__ b2,
    float* __restrict__ out)
{
    __shared__ float sc[NF], sh[NF], W2s[6 * NF], b2s[6];
    const int tid = threadIdx.x;
    if (tid < NF) {
        const float invN = 1.f / (float)NTOT;
        float mu = gsum[tid] * invN;
        float var = gsq[tid] * invN - mu * mu;
        float iv = rsqrtf(var + 1e-5f);
        float s = gamma[tid] * iv;
        sc[tid] = s;
        sh[tid] = beta[tid] - mu * s;
    }
    for (int i = tid; i < 6 * NF; i += 256) W2s[i] = W2[i];
    if (tid < 6) b2s[tid] = b2[tid];
    __syncthreads();

    size_t n = (size_t)blockIdx.x * 256 + tid;
    const h2_t* yr = (const h2_t*)(ybuf + n * NF);
    float a0 = b2s[0], a1 = b2s[1], a2 = b2s[2], a3 = b2s[3], a4 = b2s[4], a5 = b2s[5];
    #pragma unroll 8
    for (int p = 0; p < 64; ++p) {
        h2_t v = yr[p];
        int f0 = 2 * p, f1 = 2 * p + 1;
        float v0 = fmaxf(fmaf((float)v.x, sc[f0], sh[f0]), 0.f);
        float v1 = fmaxf(fmaf((float)v.y, sc[f1], sh[f1]), 0.f);
        a0 = fmaf(v0, W2s[0 * NF + f0], a0); a0 = fmaf(v1, W2s[0 * NF + f1], a0);
        a1 = fmaf(v0, W2s[1 * NF + f0], a1); a1 = fmaf(v1, W2s[1 * NF + f1], a1);
        a2 = fmaf(v0, W2s[2 * NF + f0], a2); a2 = fmaf(v1, W2s[2 * NF + f1], a2);
        a3 = fmaf(v0, W2s[3 * NF + f0], a3); a3 = fmaf(v1, W2s[3 * NF + f1], a3);
        a4 = fmaf(v0, W2s[4 * NF + f0], a4); a4 = fmaf(v1, W2s[4 * NF + f1], a4);
        a5 = fmaf(v0, W2s[5 * NF + f0], a5); a5 = fmaf(v1, W2s[5 * NF + f1], a5);
    }
    float* op = out + n * 6;
    op[0] = a0; op[1] = a1; op[2] = a2; op[3] = a3; op[4] = a4; op[5] = a5;
}

extern "C" void kernel_launch(void* const* d_in, const int* in_sizes, int n_in,
                              void* d_out, int out_size, void* d_ws, size_t ws_size,
                              hipStream_t stream) {
    const float* audio = (const float*)d_in[1];
    const float* s_rt  = (const float*)d_in[2];
    const float* Wih0  = (const float*)d_in[3];
    const float* Whh0  = (const float*)d_in[4];
    const float* bih0  = (const float*)d_in[5];
    const float* bhh0  = (const float*)d_in[6];
    const float* Wih1  = (const float*)d_in[7];
    const float* Whh1  = (const float*)d_in[8];
    const float* bih1  = (const float*)d_in[9];
    const float* bhh1  = (const float*)d_in[10];
    const float* W1    = (const float*)d_in[11];
    const float* b1    = (const float*)d_in[12];
    const float* gamma = (const float*)d_in[13];
    const float* beta  = (const float*)d_in[14];
    const float* W2    = (const float*)d_in[15];
    const float* b2    = (const float*)d_in[16];

    char* ws = (char*)d_ws;
    f16* WF0   = (f16*)(ws + OFF_WF0);
    f16* WF1   = (f16*)(ws + OFF_WF1);
    f16* WH    = (f16*)(ws + OFF_WH);
    float* gsum = (float*)(ws + OFF_GSUM);
    float* gsq  = (float*)(ws + OFF_GSQ);
    u32* ctrp   = (u32*)(ws + OFF_CTR);
    f16* gh1    = (f16*)(ws + OFF_GH1);
    f16* gh2    = (f16*)(ws + OFF_GH2);
    f16* ybuf   = (f16*)(ws + OFF_Y);
    float* out  = (float*)d_out;

    // prep: 794624 + 532480 + 33792 + 256 + 512 = 1,361,664 = 5319 * 256
    prep_kernel<<<5319, 256, 0, stream>>>(Wih0, Whh0, Wih1, Whh1, W1,
                                          WF0, WF1, WH, gsum, ctrp);

    lstm_group_kernel<<<256, 512, 0, stream>>>(audio, s_rt,
                                               (const u32*)WF0, (const u32*)WF1, (const u32*)WH,
                                               bih0, bhh0, bih1, bhh1, b1,
                                               gh1, gh2, ctrp, ybuf, gsum, gsq);

    head_kernel<<<NTOT / 256, 256, 0, stream>>>(ybuf, gsum, gsq, gamma, beta, W2, b2, out);
}

// Round 4
// 3564.842 us; speedup vs baseline: 6.1808x; 1.8775x over previous
//
#include <hip/hip_runtime.h>
#include <stdint.h>

typedef unsigned int u32;
typedef unsigned long long u64;
typedef _Float16 f16;
typedef _Float16 h2_t __attribute__((ext_vector_type(2)));
typedef _Float16 f16x4 __attribute__((ext_vector_type(4)));
typedef _Float16 f16x8 __attribute__((ext_vector_type(8)));
typedef float f32x4 __attribute__((ext_vector_type(4)));
typedef float f32x16 __attribute__((ext_vector_type(16)));

#define TT 512
#define NF 128
#define NTOT (256 * TT)

// ---- ws layout (bytes) ----
#define OFF_WA0   0u          // 786432 f16 = 1,572,864
#define OFF_WA1   1572864u    // 524288 f16 = 1,048,576
#define OFF_WAH   2621440u    // 131072 f16 =   262,144
#define OFF_GSUM  2883584u    // 128 f32 (+pad)
#define OFF_GSQ   2884096u    // 128 f32 (+pad)
#define OFF_CTR   2884608u    // 512 u32
#define OFF_GH1   2886656u    // 131072 B
#define OFF_GH2   3017728u    // 131072 B
#define OFF_Y     3148800u    // 131072*128 f16 = 33,554,432

__device__ __forceinline__ float sigf(float x) { return 1.0f / (1.0f + __expf(-x)); }
__device__ __forceinline__ float tanh_fast(float x) { return 1.0f - 2.0f / (__expf(2.0f * x) + 1.0f); }

// ---------------- prep: pack weights into per-wave MFMA A-fragments ----------------
// Fragment k-convention kappa(h,j) = 8h + j (h = lane>>5 for 32x32, lane>>4 for 16x16).
// Same convention is used for B-loads in the main kernel => self-consistent.
__global__ void prep_kernel(const float* __restrict__ Wih0, const float* __restrict__ Whh0,
                            const float* __restrict__ Wih1, const float* __restrict__ Whh1,
                            const float* __restrict__ W1,
                            f16* __restrict__ WA0, f16* __restrict__ WA1, f16* __restrict__ WAH,
                            float* __restrict__ gz, u32* __restrict__ ctr) {
    int idx = blockIdx.x * 256 + threadIdx.x;
    const int n0 = 786432, n1 = 524288, n2 = 131072;
    if (idx < n0) {
        int u = idx >> 9, r9 = idx & 511;
        int lane = r9 >> 3, j = r9 & 7;
        int ks = u % 6; u /= 6;
        int kw = u & 7, w = u >> 3;
        int lr = lane & 31, h = lane >> 5;
        int r = ((lr >> 3) << 8) + 8 * w + (lr & 7);
        int c = 96 * kw + 16 * ks + 8 * h + j;
        float v = (c < 512) ? Wih0[r * 512 + c] : Whh0[r * 256 + (c - 512)];
        WA0[idx] = (f16)v;
    } else if (idx < n0 + n1) {
        int i2 = idx - n0;
        int u = i2 >> 9, r9 = i2 & 511;
        int lane = r9 >> 3, j = r9 & 7;
        int ks = u & 3; u >>= 2;
        int kw = u & 7, w = u >> 3;
        int lr = lane & 31, h = lane >> 5;
        int r = ((lr >> 3) << 8) + 8 * w + (lr & 7);
        int k = 64 * kw + 16 * ks + 8 * h + j;
        float v = (k < 256) ? Wih1[r * 256 + k] : Whh1[r * 256 + (k - 256)];
        WA1[i2] = (f16)v;
    } else if (idx < n0 + n1 + n2) {
        int i2 = idx - n0 - n1;
        int u = i2 >> 9, r9 = i2 & 511;
        int lane = r9 >> 3, j = r9 & 7;
        int ks = u & 7, w = u >> 3;
        int m = lane & 15, hh = lane >> 4;
        int k = 32 * ks + 8 * hh + j;
        float v = (m < 4) ? W1[(4 * w + m) * 256 + k] : 0.f;
        WAH[i2] = (f16)v;
    } else if (idx < n0 + n1 + n2 + 256) {
        gz[idx - n0 - n1 - n2] = 0.f;     // gsum[128] then gsq[128] (contiguous)
    } else if (idx < n0 + n1 + n2 + 256 + 512) {
        ctr[idx - n0 - n1 - n2 - 256] = 0u;
    }
}

#define MFMA32(A, BP, C) (C) = __builtin_amdgcn_mfma_f32_32x32x16_f16( \
    __builtin_bit_cast(f16x8, (A)), __builtin_bit_cast(f16x8, *(const uint4*)(BP)), (C), 0, 0, 0)

#define ZZWR(KW, C) do { \
    f32x4 v0_ = {(C)[0], (C)[1], (C)[2], (C)[3]};    *(f32x4*)&zz[KW][n32][4 * h32] = v0_; \
    f32x4 v1_ = {(C)[4], (C)[5], (C)[6], (C)[7]};    *(f32x4*)&zz[KW][n32][8 + 4 * h32] = v1_; \
    f32x4 v2_ = {(C)[8], (C)[9], (C)[10], (C)[11]};  *(f32x4*)&zz[KW][n32][16 + 4 * h32] = v2_; \
    f32x4 v3_ = {(C)[12], (C)[13], (C)[14], (C)[15]}; *(f32x4*)&zz[KW][n32][24 + 4 * h32] = v3_; } while (0)

// ---------------- main: 8 groups x 32 row-slice WGs; weights register-resident ----
__global__ __launch_bounds__(512) void lstm_group_kernel(
    const float* __restrict__ audio, const float* __restrict__ s_rt,
    const uint4* __restrict__ WA0, const uint4* __restrict__ WA1, const uint4* __restrict__ WAH,
    const float* __restrict__ bih0, const float* __restrict__ bhh0,
    const float* __restrict__ bih1, const float* __restrict__ bhh1,
    const float* __restrict__ b1,
    f16* __restrict__ gh1, f16* __restrict__ gh2, u32* __restrict__ ctr,
    f16* __restrict__ ybuf, float* __restrict__ gsum, float* __restrict__ gsq)
{
    __shared__ f16 X[32][776];         // [b][ h2/prev_out(256) | a_t(256) | h1(256) + pad ]
    __shared__ float zz[8][32][36];    // [kw][batch][m-rows padded]
    __shared__ f16 hst[32][8];
    __shared__ float bc0s[32], bc1s[32], b1s[4];

    const int tid = threadIdx.x;
    const int w = blockIdx.x >> 3;     // row-slice 0..31
    const int g = blockIdx.x & 7;      // group 0..7 (XCD-local: bid%8)
    const int wv = tid >> 6;
    const int lane = tid & 63;
    const int n32 = lane & 31;
    const int h32 = (lane >> 5) & 1;
    const int cb = tid >> 3, cj = tid & 7;   // cell-update mapping (tid<256)

    // ---- persistent A-fragments ----
    uint4 a0[6], a1[4], ah[8] = {};
    #pragma unroll
    for (int ks = 0; ks < 6; ++ks) a0[ks] = WA0[((w * 8 + wv) * 6 + ks) * 64 + lane];
    #pragma unroll
    for (int ks = 0; ks < 4; ++ks) a1[ks] = WA1[((w * 8 + wv) * 4 + ks) * 64 + lane];
    if (wv == 0) {
        #pragma unroll
        for (int ks = 0; ks < 8; ++ks) ah[ks] = WAH[(w * 8 + ks) * 64 + lane];
    }

    if (tid < 32) {
        int r = ((tid >> 3) << 8) + 8 * w + (tid & 7);
        bc0s[tid] = bih0[r] + bhh0[r];
        bc1s[tid] = bih1[r] + bhh1[r];
    }
    if (tid < 4) b1s[tid] = b1[4 * w + tid];

    // ---- init X: prev_out = mean(s_rt), a_0, h1 = 0 ----
    for (int it = tid; it < 32 * 256; it += 512) {
        int b = it >> 8, c = it & 255;
        const float* sp = s_rt + ((size_t)(32 * g + b) * 16) * 256 + c;
        float s = 0.f;
        #pragma unroll
        for (int l = 0; l < 16; ++l) s += sp[l * 256];
        X[b][c] = (f16)(s * 0.0625f);
        X[b][256 + c] = (f16)audio[((size_t)(32 * g + b) * 512) * 256 + c];
    }
    for (int it = tid; it < 32 * 128; it += 512) {
        int b = it >> 7, q = it & 127;
        ((u32*)&X[b][512])[q] = 0u;
    }
    float c1 = 0.f, c2 = 0.f;
    float ys0 = 0, ys1 = 0, ys2 = 0, ys3 = 0, yq0 = 0, yq1 = 0, yq2 = 0, yq3 = 0;
    __syncthreads();

    u32* ctr1 = ctr + (g * 2 + 0) * 32;
    u32* ctr2 = ctr + (g * 2 + 1) * 32;
    u64* gh1u = (u64*)gh1;
    u64* gh2u = (u64*)gh2;

    for (int t = 0; t < TT; ++t) {
        // prefetch audio(t+1) into registers
        float4 av0, av1, av2, av3;
        if (t + 1 < TT) {
            const float4* a4 = (const float4*)audio;
            int b0 = tid >> 6, q0 = tid & 63;
            size_t base = ((size_t)(t + 1)) * 64 + q0;
            av0 = a4[(size_t)(32 * g + b0) * 32768 + base];
            av1 = a4[(size_t)(32 * g + b0 + 8) * 32768 + base];
            av2 = a4[(size_t)(32 * g + b0 + 16) * 32768 + base];
            av3 = a4[(size_t)(32 * g + b0 + 24) * 32768 + base];
        }
        // ---- A: layer0 gates, full K=768, K-split over 8 waves ----
        {
            f32x16 C = {};
            #pragma unroll
            for (int ks = 0; ks < 6; ++ks)
                MFMA32(a0[ks], &X[n32][96 * wv + 16 * ks + 8 * h32], C);
            ZZWR(wv, C);
        }
        __syncthreads();
        // ---- B: cell L0 (reduce 8 partials + bias + activations) ----
        if (tid < 256) {
            float z0 = bc0s[cj], z1 = bc0s[8 + cj], z2 = bc0s[16 + cj], z3 = bc0s[24 + cj];
            #pragma unroll
            for (int kw = 0; kw < 8; ++kw) {
                z0 += zz[kw][cb][cj];      z1 += zz[kw][cb][8 + cj];
                z2 += zz[kw][cb][16 + cj]; z3 += zz[kw][cb][24 + cj];
            }
            float c = sigf(z1) * c1 + sigf(z0) * tanh_fast(z2);
            c1 = c;
            hst[cb][cj] = (f16)(sigf(z3) * tanh_fast(c));
        }
        __syncthreads();
        // ---- publish h1 + barrier1; waves 4..7 overlap L1 h2-half ----
        if (tid < 64) {
            u64 v = ((const u64*)hst)[tid];
            __hip_atomic_store(gh1u + (size_t)(g * 32 + (tid >> 1)) * 64 + 2 * w + (tid & 1), v,
                               __ATOMIC_RELAXED, __HIP_MEMORY_SCOPE_AGENT);
            asm volatile("s_waitcnt vmcnt(0)" ::: "memory");
        }
        if (tid == 0)
            __hip_atomic_fetch_add(ctr1, 1u, __ATOMIC_RELAXED, __HIP_MEMORY_SCOPE_AGENT);
        if (wv >= 4) {
            f32x16 C = {};
            if (t > 0) {
                #pragma unroll
                for (int ks = 0; ks < 4; ++ks)
                    MFMA32(a1[ks], &X[n32][64 * (wv - 4) + 16 * ks + 8 * h32], C);
            }
            ZZWR(wv, C);
        }
        if (tid == 0) {
            u32 tgt = 32u * (u32)(t + 1);
            int guard_ = 0;
            while (__hip_atomic_load(ctr1, __ATOMIC_RELAXED, __HIP_MEMORY_SCOPE_AGENT) < tgt
                   && ++guard_ < 200000000) { __builtin_amdgcn_s_sleep(2); }
        }
        __syncthreads();
        // ---- C: gather h1(t) -> X[512..768) ----
        {
            int b0 = tid >> 6, q0 = tid & 63;
            #pragma unroll
            for (int s = 0; s < 4; ++s) {
                int b = b0 + 8 * s;
                u64 v = __hip_atomic_load(gh1u + (size_t)(g * 32 + b) * 64 + q0,
                                          __ATOMIC_RELAXED, __HIP_MEMORY_SCOPE_AGENT);
                *(u64*)&X[b][512 + 4 * q0] = v;
            }
        }
        __syncthreads();
        // ---- D: L1 h1-half (waves 0..3) ----
        if (wv < 4) {
            f32x16 C = {};
            #pragma unroll
            for (int ks = 0; ks < 4; ++ks)
                MFMA32(a1[ks], &X[n32][512 + 64 * wv + 16 * ks + 8 * h32], C);
            ZZWR(wv, C);
        }
        __syncthreads();
        // ---- E: cell L1 ----
        if (tid < 256) {
            float z0 = bc1s[cj], z1 = bc1s[8 + cj], z2 = bc1s[16 + cj], z3 = bc1s[24 + cj];
            #pragma unroll
            for (int kw = 0; kw < 8; ++kw) {
                z0 += zz[kw][cb][cj];      z1 += zz[kw][cb][8 + cj];
                z2 += zz[kw][cb][16 + cj]; z3 += zz[kw][cb][24 + cj];
            }
            float c = sigf(z1) * c2 + sigf(z0) * tanh_fast(z2);
            c2 = c;
            hst[cb][cj] = (f16)(sigf(z3) * tanh_fast(c));
        }
        __syncthreads();
        // ---- publish h2 + barrier2 ----
        if (tid < 64) {
            u64 v = ((const u64*)hst)[tid];
            __hip_atomic_store(gh2u + (size_t)(g * 32 + (tid >> 1)) * 64 + 2 * w + (tid & 1), v,
                               __ATOMIC_RELAXED, __HIP_MEMORY_SCOPE_AGENT);
            asm volatile("s_waitcnt vmcnt(0)" ::: "memory");
        }
        if (tid == 0) {
            __hip_atomic_fetch_add(ctr2, 1u, __ATOMIC_RELAXED, __HIP_MEMORY_SCOPE_AGENT);
            u32 tgt = 32u * (u32)(t + 1);
            int guard_ = 0;
            while (__hip_atomic_load(ctr2, __ATOMIC_RELAXED, __HIP_MEMORY_SCOPE_AGENT) < tgt
                   && ++guard_ < 200000000) { __builtin_amdgcn_s_sleep(2); }
        }
        __syncthreads();
        // ---- F: gather h2(t) -> X[0..256); audio(t+1) -> X[256..512) ----
        {
            int b0 = tid >> 6, q0 = tid & 63;
            #pragma unroll
            for (int s = 0; s < 4; ++s) {
                int b = b0 + 8 * s;
                u64 v = __hip_atomic_load(gh2u + (size_t)(g * 32 + b) * 64 + q0,
                                          __ATOMIC_RELAXED, __HIP_MEMORY_SCOPE_AGENT);
                *(u64*)&X[b][4 * q0] = v;
            }
            if (t + 1 < TT) {
                #define AST(AV, S) do { \
                    int b_ = (tid >> 6) + 8 * (S); int q_ = tid & 63; \
                    h2_t p0_; p0_.x = (f16)(AV).x; p0_.y = (f16)(AV).y; \
                    h2_t p1_; p1_.x = (f16)(AV).z; p1_.y = (f16)(AV).w; \
                    uint2 pv_; pv_.x = __builtin_bit_cast(u32, p0_); pv_.y = __builtin_bit_cast(u32, p1_); \
                    *(uint2*)&X[b_][256 + 4 * q_] = pv_; } while (0)
                AST(av0, 0); AST(av1, 1); AST(av2, 2); AST(av3, 3);
            }
        }
        __syncthreads();
        // ---- G: head on wave 0 (16x16x32, M=4 padded); others run ahead into A(t+1) ----
        if (wv == 0) {
            #pragma unroll
            for (int nt = 0; nt < 2; ++nt) {
                f32x4 C = {};
                #pragma unroll
                for (int ks = 0; ks < 8; ++ks)
                    C = __builtin_amdgcn_mfma_f32_16x16x32_f16(
                        __builtin_bit_cast(f16x8, ah[ks]),
                        __builtin_bit_cast(f16x8,
                            *(const uint4*)&X[nt * 16 + (lane & 15)][32 * ks + 8 * ((lane >> 4) & 3)]),
                        C, 0, 0, 0);
                if (lane < 16) {
                    float y0 = C[0] + b1s[0], y1 = C[1] + b1s[1];
                    float y2 = C[2] + b1s[2], y3 = C[3] + b1s[3];
                    ys0 += y0; yq0 += y0 * y0; ys1 += y1; yq1 += y1 * y1;
                    ys2 += y2; yq2 += y2 * y2; ys3 += y3; yq3 += y3 * y3;
                    f16x4 yp; yp[0] = (f16)y0; yp[1] = (f16)y1; yp[2] = (f16)y2; yp[3] = (f16)y3;
                    int b = nt * 16 + lane;
                    ((u64*)ybuf)[((size_t)(g * 32 + b) * 512 + t) * 32 + w] = __builtin_bit_cast(u64, yp);
                }
            }
        }
    }
    // ---- BN stats reduce (wave 0, lanes 0..15) ----
    if (wv == 0 && lane < 16) {
        #pragma unroll
        for (int m = 8; m >= 1; m >>= 1) {
            ys0 += __shfl_xor(ys0, m, 64); ys1 += __shfl_xor(ys1, m, 64);
            ys2 += __shfl_xor(ys2, m, 64); ys3 += __shfl_xor(ys3, m, 64);
            yq0 += __shfl_xor(yq0, m, 64); yq1 += __shfl_xor(yq1, m, 64);
            yq2 += __shfl_xor(yq2, m, 64); yq3 += __shfl_xor(yq3, m, 64);
        }
        if (lane == 0) {
            atomicAdd(&gsum[4 * w + 0], ys0); atomicAdd(&gsum[4 * w + 1], ys1);
            atomicAdd(&gsum[4 * w + 2], ys2); atomicAdd(&gsum[4 * w + 3], ys3);
            atomicAdd(&gsq[4 * w + 0], yq0); atomicAdd(&gsq[4 * w + 1], yq1);
            atomicAdd(&gsq[4 * w + 2], yq2); atomicAdd(&gsq[4 * w + 3], yq3);
        }
    }
}

// ---------------- final head: BN(train) + ReLU + Linear(128->6) ----------------
__global__ __launch_bounds__(256) void head_kernel(
    const f16* __restrict__ ybuf, const float* __restrict__ gsum, const float* __restrict__ gsq,
    const float* __restrict__ gamma, const float* __restrict__ beta,
    const float* __restrict__ W2, const float* __restrict__ b2,
    float* __restrict__ out)
{
    __shared__ float sc[NF], sh[NF], W2s[6 * NF], b2s[6];
    const int tid = threadIdx.x;
    if (tid < NF) {
        const float invN = 1.f / (float)NTOT;
        float mu = gsum[tid] * invN;
        float var = gsq[tid] * invN - mu * mu;
        float iv = rsqrtf(var + 1e-5f);
        float s = gamma[tid] * iv;
        sc[tid] = s;
        sh[tid] = beta[tid] - mu * s;
    }
    for (int i = tid; i < 6 * NF; i += 256) W2s[i] = W2[i];
    if (tid < 6) b2s[tid] = b2[tid];
    __syncthreads();

    size_t n = (size_t)blockIdx.x * 256 + tid;
    const h2_t* yr = (const h2_t*)(ybuf + n * NF);
    float a0 = b2s[0], a1 = b2s[1], a2 = b2s[2], a3 = b2s[3], a4 = b2s[4], a5 = b2s[5];
    #pragma unroll 8
    for (int p = 0; p < 64; ++p) {
        h2_t v = yr[p];
        int f0 = 2 * p, f1 = 2 * p + 1;
        float v0 = fmaxf(fmaf((float)v.x, sc[f0], sh[f0]), 0.f);
        float v1 = fmaxf(fmaf((float)v.y, sc[f1], sh[f1]), 0.f);
        a0 = fmaf(v0, W2s[0 * NF + f0], a0); a0 = fmaf(v1, W2s[0 * NF + f1], a0);
        a1 = fmaf(v0, W2s[1 * NF + f0], a1); a1 = fmaf(v1, W2s[1 * NF + f1], a1);
        a2 = fmaf(v0, W2s[2 * NF + f0], a2); a2 = fmaf(v1, W2s[2 * NF + f1], a2);
        a3 = fmaf(v0, W2s[3 * NF + f0], a3); a3 = fmaf(v1, W2s[3 * NF + f1], a3);
        a4 = fmaf(v0, W2s[4 * NF + f0], a4); a4 = fmaf(v1, W2s[4 * NF + f1], a4);
        a5 = fmaf(v0, W2s[5 * NF + f0], a5); a5 = fmaf(v1, W2s[5 * NF + f1], a5);
    }
    float* op = out + n * 6;
    op[0] = a0; op[1] = a1; op[2] = a2; op[3] = a3; op[4] = a4; op[5] = a5;
}

extern "C" void kernel_launch(void* const* d_in, const int* in_sizes, int n_in,
                              void* d_out, int out_size, void* d_ws, size_t ws_size,
                              hipStream_t stream) {
    const float* audio = (const float*)d_in[1];
    const float* s_rt  = (const float*)d_in[2];
    const float* Wih0  = (const float*)d_in[3];
    const float* Whh0  = (const float*)d_in[4];
    const float* bih0  = (const float*)d_in[5];
    const float* bhh0  = (const float*)d_in[6];
    const float* Wih1  = (const float*)d_in[7];
    const float* Whh1  = (const float*)d_in[8];
    const float* bih1  = (const float*)d_in[9];
    const float* bhh1  = (const float*)d_in[10];
    const float* W1    = (const float*)d_in[11];
    const float* b1    = (const float*)d_in[12];
    const float* gamma = (const float*)d_in[13];
    const float* beta  = (const float*)d_in[14];
    const float* W2    = (const float*)d_in[15];
    const float* b2    = (const float*)d_in[16];

    char* ws = (char*)d_ws;
    f16* WA0    = (f16*)(ws + OFF_WA0);
    f16* WA1    = (f16*)(ws + OFF_WA1);
    f16* WAH    = (f16*)(ws + OFF_WAH);
    float* gsum = (float*)(ws + OFF_GSUM);
    float* gsq  = (float*)(ws + OFF_GSQ);
    u32* ctrp   = (u32*)(ws + OFF_CTR);
    f16* gh1    = (f16*)(ws + OFF_GH1);
    f16* gh2    = (f16*)(ws + OFF_GH2);
    f16* ybuf   = (f16*)(ws + OFF_Y);
    float* out  = (float*)d_out;

    // prep: 786432 + 524288 + 131072 + 256 + 512 = 1,442,560 = 5635 * 256
    prep_kernel<<<5635, 256, 0, stream>>>(Wih0, Whh0, Wih1, Whh1, W1,
                                          WA0, WA1, WAH, gsum, ctrp);

    lstm_group_kernel<<<256, 512, 0, stream>>>(audio, s_rt,
                                               (const uint4*)WA0, (const uint4*)WA1, (const uint4*)WAH,
                                               bih0, bhh0, bih1, bhh1, b1,
                                               gh1, gh2, ctrp, ybuf, gsum, gsq);

    head_kernel<<<NTOT / 256, 256, 0, stream>>>(ybuf, gsum, gsq, gamma, beta, W2, b2, out);
}